// Round 1
// baseline (5939.123 us; speedup 1.0000x reference)
//
#include <hip/hip_runtime.h>
#include <hip/hip_fp16.h>

#define B_  64
#define T_  2048
#define I_  64
#define H_  256
#define G4_ 1024   // 4*H

typedef _Float16 h2v __attribute__((ext_vector_type(2)));

__device__ __forceinline__ float fdot2(uint32_t a, uint32_t b, float c) {
#if __has_builtin(__builtin_amdgcn_fdot2)
    return __builtin_amdgcn_fdot2(__builtin_bit_cast(h2v, a), __builtin_bit_cast(h2v, b), c, false);
#else
    h2v ha = __builtin_bit_cast(h2v, a), hb = __builtin_bit_cast(h2v, b);
    return c + (float)ha.x * (float)hb.x + (float)ha.y * (float)hb.y;
#endif
}

__device__ __forceinline__ ushort f2h(float v) {
    return __builtin_bit_cast(ushort, (_Float16)v);
}
__device__ __forceinline__ float h2f(ushort v) {
    return (float)__builtin_bit_cast(_Float16, v);
}

// ---------------------------------------------------------------------------
// Repack W_hh fp32 [1024][256] -> f16 wpk[g][kc][h][j]  (g=gate, kc=K/8 chunk,
// h=hdim 0..255, j=0..7).  Makes the LSTM kernel's per-thread register preload
// a coalesced 16B/lane load.
// ---------------------------------------------------------------------------
__global__ void repack_kernel(const float* __restrict__ Whh, ushort* __restrict__ wpk) {
    int o  = blockIdx.x * 256 + threadIdx.x;   // 0 .. 262143
    int j  = o & 7;
    int h  = (o >> 3) & 255;
    int kc = (o >> 11) & 31;
    int g  = o >> 16;
    float v = Whh[(g * 256 + h) * 256 + kc * 8 + j];
    wpk[o] = f2h(v);
}

// ---------------------------------------------------------------------------
// gx = x @ W_ih^T + b_ih + b_hh  (f16 out), for one chunk of TCc timesteps.
// grid = ((64*TCc)/32, 4), block = 256.  Tile: 32 (b,t) rows x 256 gate rows.
// ---------------------------------------------------------------------------
__global__ __launch_bounds__(256) void gx_kernel(
    const float* __restrict__ x, const float* __restrict__ Wih,
    const float* __restrict__ bih, const float* __restrict__ bhh,
    ushort* __restrict__ gx, int t0, int TCc) {

    __shared__ float xs[32][64];
    const int bt0 = blockIdx.x * 32;
    const int row = blockIdx.y * 256 + threadIdx.x;

    for (int i = threadIdx.x; i < 32 * 64; i += 256) {
        int bt = bt0 + (i >> 6);
        int b  = bt / TCc;
        int tl = bt - b * TCc;
        xs[i >> 6][i & 63] = x[((size_t)(b * T_) + t0 + tl) * I_ + (i & 63)];
    }
    __syncthreads();

    float w[64];
#pragma unroll
    for (int k = 0; k < 64; ++k) w[k] = Wih[row * I_ + k];
    const float bias = bih[row] + bhh[row];

    for (int i = 0; i < 32; ++i) {
        float acc = bias;
#pragma unroll
        for (int k = 0; k < 64; ++k) acc = fmaf(w[k], xs[i][k], acc);
        gx[(size_t)(bt0 + i) * G4_ + row] = f2h(acc);
    }
}

// ---------------------------------------------------------------------------
// Persistent per-batch LSTM.  64 blocks x 256 threads (4 waves, 1 wave/SIMD,
// 512-VGPR budget).  Thread t owns gate rows i[t],f[t],g[t] in registers
// (3 x 128 packed-f16 dwords) and o[t] in LDS (128 KB, XOR-swizzled).
// c[t], h[t] live in thread t's registers; h broadcast via 512B LDS buffer.
// ---------------------------------------------------------------------------
__global__ __launch_bounds__(256, 1) void lstm_kernel(
    const ushort* __restrict__ wpk, const ushort* __restrict__ gx,
    const float* __restrict__ Wo, const float* __restrict__ bo,
    float* __restrict__ state,     // [2][64][256]: c then h
    float* __restrict__ out, int t0, int TCc, int first) {

    __shared__ __align__(16) ushort wg4[256 * 256];  // o-gate rows, 128 KB
    __shared__ __align__(16) ushort hs[256];         // h(t-1) as f16
    __shared__ float red[4];

    const int tid = threadIdx.x;
    const int b   = blockIdx.x;
    const int tmask = tid & 31;

    // --- preload i/f/g gate rows into registers (coalesced 16B/lane) ---
    uint32_t wi[128], wf[128], wg[128];
#pragma unroll
    for (int kc = 0; kc < 32; ++kc) {
        uint4 v = *(const uint4*)(wpk + (size_t)(0 * 32 + kc) * 2048 + tid * 8);
        wi[kc * 4 + 0] = v.x; wi[kc * 4 + 1] = v.y; wi[kc * 4 + 2] = v.z; wi[kc * 4 + 3] = v.w;
    }
#pragma unroll
    for (int kc = 0; kc < 32; ++kc) {
        uint4 v = *(const uint4*)(wpk + (size_t)(1 * 32 + kc) * 2048 + tid * 8);
        wf[kc * 4 + 0] = v.x; wf[kc * 4 + 1] = v.y; wf[kc * 4 + 2] = v.z; wf[kc * 4 + 3] = v.w;
    }
#pragma unroll
    for (int kc = 0; kc < 32; ++kc) {
        uint4 v = *(const uint4*)(wpk + (size_t)(2 * 32 + kc) * 2048 + tid * 8);
        wg[kc * 4 + 0] = v.x; wg[kc * 4 + 1] = v.y; wg[kc * 4 + 2] = v.z; wg[kc * 4 + 3] = v.w;
    }
    // --- o-gate rows into LDS, 16B-unit XOR swizzle for bank balance ---
    for (int kc = 0; kc < 32; ++kc) {
        uint4 v = *(const uint4*)(wpk + (size_t)(3 * 32 + kc) * 2048 + tid * 8);
        int u = kc ^ tmask;
        *(uint4*)(wg4 + tid * 256 + u * 8) = v;
    }

    const float Wop = Wo[tid];
    const float bov = bo[0];

    float c, h;
    if (first) { c = 0.f; h = 0.f; }
    else {
        c = state[b * H_ + tid];
        h = state[B_ * H_ + b * H_ + tid];
    }
    hs[tid] = f2h(h);
    __syncthreads();

    const ushort* gxb = gx + (size_t)b * TCc * G4_;

    ushort c_i = gxb[tid];
    ushort c_f = gxb[256 + tid];
    ushort c_g = gxb[512 + tid];
    ushort c_o = gxb[768 + tid];

    for (int tl = 0; tl < TCc; ++tl) {
        // prefetch next step's gx (latency hidden under the dot loop)
        const int tn = (tl + 1 < TCc) ? tl + 1 : tl;
        const size_t nb = (size_t)tn * G4_;
        ushort n_i = gxb[nb + tid];
        ushort n_f = gxb[nb + 256 + tid];
        ushort n_g = gxb[nb + 512 + tid];
        ushort n_o = gxb[nb + 768 + tid];

        float ai = h2f(c_i), af = h2f(c_f), ag = h2f(c_g), ao = h2f(c_o);

#pragma unroll
        for (int kc = 0; kc < 32; ++kc) {
            uint4 hq = *(const uint4*)(hs + kc * 8);                 // broadcast
            int u = kc ^ tmask;
            uint4 wo = *(const uint4*)(wg4 + tid * 256 + u * 8);     // per-lane
            ai = fdot2(wi[kc * 4 + 0], hq.x, ai);
            ai = fdot2(wi[kc * 4 + 1], hq.y, ai);
            ai = fdot2(wi[kc * 4 + 2], hq.z, ai);
            ai = fdot2(wi[kc * 4 + 3], hq.w, ai);
            af = fdot2(wf[kc * 4 + 0], hq.x, af);
            af = fdot2(wf[kc * 4 + 1], hq.y, af);
            af = fdot2(wf[kc * 4 + 2], hq.z, af);
            af = fdot2(wf[kc * 4 + 3], hq.w, af);
            ag = fdot2(wg[kc * 4 + 0], hq.x, ag);
            ag = fdot2(wg[kc * 4 + 1], hq.y, ag);
            ag = fdot2(wg[kc * 4 + 2], hq.z, ag);
            ag = fdot2(wg[kc * 4 + 3], hq.w, ag);
            ao = fdot2(wo.x, hq.x, ao);
            ao = fdot2(wo.y, hq.y, ao);
            ao = fdot2(wo.z, hq.z, ao);
            ao = fdot2(wo.w, hq.w, ao);
        }

        // elementwise cell update (fp32)
        float si = __builtin_amdgcn_rcpf(1.f + __expf(-ai));
        float sf = __builtin_amdgcn_rcpf(1.f + __expf(-af));
        float so = __builtin_amdgcn_rcpf(1.f + __expf(-ao));
        float eg = __expf(2.f * ag);
        float tg = (eg - 1.f) * __builtin_amdgcn_rcpf(eg + 1.f);
        c = sf * c + si * tg;
        float ec = __expf(2.f * c);
        float tc = (ec - 1.f) * __builtin_amdgcn_rcpf(ec + 1.f);
        h = so * tc;

        // output projection partial + wave butterfly reduce
        float p = h * Wop;
#pragma unroll
        for (int m = 1; m < 64; m <<= 1) p += __shfl_xor(p, m, 64);

        __syncthreads();                 // all reads of hs(t-1) done
        hs[tid] = f2h(h);
        if ((tid & 63) == 0) red[tid >> 6] = p;
        __syncthreads();                 // hs(t) + red visible
        if (tid == 0)
            out[b * T_ + t0 + tl] = red[0] + red[1] + red[2] + red[3] + bov;

        c_i = n_i; c_f = n_f; c_g = n_g; c_o = n_o;
    }

    state[b * H_ + tid]        = c;
    state[B_ * H_ + b * H_ + tid] = h;
}

// ---------------------------------------------------------------------------
extern "C" void kernel_launch(void* const* d_in, const int* in_sizes, int n_in,
                              void* d_out, int out_size, void* d_ws, size_t ws_size,
                              hipStream_t stream) {
    const float* x   = (const float*)d_in[0];
    const float* Wih = (const float*)d_in[1];
    const float* Whh = (const float*)d_in[2];
    const float* bih = (const float*)d_in[3];
    const float* bhh = (const float*)d_in[4];
    const float* Wo  = (const float*)d_in[5];
    const float* bo  = (const float*)d_in[6];
    float* out = (float*)d_out;

    char* ws = (char*)d_ws;
    ushort* wpk  = (ushort*)ws;                              // 512 KB
    float*  state = (float*)(ws + 512 * 1024);               // 128 KB
    ushort* gxb  = (ushort*)(ws + 512 * 1024 + 128 * 1024);  // rest: gx chunks

    size_t avail = (ws_size > 640 * 1024) ? ws_size - 640 * 1024 : 0;
    long long tcmax = (long long)(avail / ((size_t)B_ * G4_ * 2));
    int TC = (tcmax > T_) ? T_ : (int)tcmax;
    TC &= ~63;               // multiple of 64
    if (TC < 64) TC = 64;    // minimum viable chunk

    repack_kernel<<<1024, 256, 0, stream>>>(Whh, wpk);

    for (int t0 = 0; t0 < T_; t0 += TC) {
        int TCc = (T_ - t0 < TC) ? (T_ - t0) : TC;
        dim3 g1((B_ * TCc) / 32, 4);
        gx_kernel<<<g1, 256, 0, stream>>>(x, Wih, bih, bhh, gxb, t0, TCc);
        lstm_kernel<<<B_, 256, 0, stream>>>(wpk, gxb, Wo, bo, state, out,
                                            t0, TCc, t0 == 0 ? 1 : 0);
    }
    (void)in_sizes; (void)n_in; (void)out_size;
}

// Round 2
// 3492.910 us; speedup vs baseline: 1.7003x; 1.7003x over previous
//
#include <hip/hip_runtime.h>
#include <hip/hip_fp16.h>

#define B_  64
#define T_  2048
#define I_  64
#define H_  256
#define G4_ 1024   // 4*H

typedef _Float16 h2v __attribute__((ext_vector_type(2)));

__device__ __forceinline__ float fdot2(uint32_t a, uint32_t b, float c) {
#if __has_builtin(__builtin_amdgcn_fdot2)
    return __builtin_amdgcn_fdot2(__builtin_bit_cast(h2v, a), __builtin_bit_cast(h2v, b), c, false);
#else
    h2v ha = __builtin_bit_cast(h2v, a), hb = __builtin_bit_cast(h2v, b);
    return c + (float)ha.x * (float)hb.x + (float)ha.y * (float)hb.y;
#endif
}

__device__ __forceinline__ ushort f2h(float v) {
    return __builtin_bit_cast(ushort, (_Float16)v);
}
__device__ __forceinline__ float h2f(ushort v) {
    return (float)__builtin_bit_cast(_Float16, v);
}

// ---------------------------------------------------------------------------
// Repack W_hh fp32 [1024][256] -> f16 wpk[g][kc][h][j]  (g=gate, kc=K/8 chunk,
// h=hdim 0..255, j=0..7).  Coalesced 16B/lane preload in the LSTM kernel.
// ---------------------------------------------------------------------------
__global__ void repack_kernel(const float* __restrict__ Whh, ushort* __restrict__ wpk) {
    int o  = blockIdx.x * 256 + threadIdx.x;   // 0 .. 262143
    int j  = o & 7;
    int h  = (o >> 3) & 255;
    int kc = (o >> 11) & 31;
    int g  = o >> 16;
    float v = Whh[(g * 256 + h) * 256 + kc * 8 + j];
    wpk[o] = f2h(v);
}

// ---------------------------------------------------------------------------
// gx = x @ W_ih^T + b_ih + b_hh  (f16 out), one chunk of TCc timesteps.
// grid = ((64*TCc)/32, 4), block = 256.  Tile: 32 (b,t) rows x 256 gate rows.
// ---------------------------------------------------------------------------
__global__ __launch_bounds__(256) void gx_kernel(
    const float* __restrict__ x, const float* __restrict__ Wih,
    const float* __restrict__ bih, const float* __restrict__ bhh,
    ushort* __restrict__ gx, int t0, int TCc) {

    __shared__ float xs[32][64];
    const int bt0 = blockIdx.x * 32;
    const int row = blockIdx.y * 256 + threadIdx.x;

    // vectorized x tile load: 512 float4
    for (int i = threadIdx.x; i < 512; i += 256) {
        int r  = i >> 4, c4 = i & 15;
        int bt = bt0 + r;
        int b  = bt / TCc;
        int tl = bt - b * TCc;
        *(float4*)(&xs[r][c4 * 4]) =
            *(const float4*)(&x[(((size_t)b * T_) + t0 + tl) * I_ + c4 * 4]);
    }
    __syncthreads();

    float w[64];
#pragma unroll
    for (int k = 0; k < 64; ++k) w[k] = Wih[row * I_ + k];
    const float bias = bih[row] + bhh[row];

    for (int i = 0; i < 32; ++i) {
        float acc = bias;
#pragma unroll
        for (int k4 = 0; k4 < 16; ++k4) {
            float4 xq = *(const float4*)(&xs[i][k4 * 4]);
            acc = fmaf(w[k4 * 4 + 0], xq.x, acc);
            acc = fmaf(w[k4 * 4 + 1], xq.y, acc);
            acc = fmaf(w[k4 * 4 + 2], xq.z, acc);
            acc = fmaf(w[k4 * 4 + 3], xq.w, acc);
        }
        gx[(size_t)(bt0 + i) * G4_ + row] = f2h(acc);
    }
}

// ---------------------------------------------------------------------------
// Persistent per-batch LSTM.  64 blocks x 512 threads (8 waves, 2/SIMD).
// Thread pair (hd, hd+256) splits K=256 in half: q = tid>>8 selects K-half.
// Each thread holds i/f/g gate half-rows in regs (3 x 64 dwords = 192 VGPR);
// o-gate half-rows live in LDS (128 KB, XOR-swizzled, conflict-free).
// q=1 passes its partial sums to q=0 via LDS; q=0 owns c,h and the update.
// h(t) is stored (f16) into the consumed gx row; projection is a later pass.
// ---------------------------------------------------------------------------
__global__ __launch_bounds__(512, 2) void lstm_kernel(
    const ushort* __restrict__ wpk, ushort* __restrict__ gx,
    float* __restrict__ state,     // [2][64][256]: c then h
    int TCc, int first) {

    __shared__ __align__(16) ushort wg4[256 * 256];  // o-gate rows, 128 KB
    __shared__ __align__(16) ushort hs[256];         // h(t-1) as f16
    __shared__ float pex[4][256];                    // q=1 -> q=0 partials

    const int tid   = threadIdx.x;
    const int hd    = tid & 255;       // owned h-dim
    const int q     = tid >> 8;        // K-half: 0 -> k 0..127, 1 -> k 128..255
    const int kbase = q << 4;          // first kc chunk (of 8 h's) for this half
    const int tmask = hd & 31;
    const int b     = blockIdx.x;
    const bool q0   = (q == 0);

    // --- preload i/f/g gate half-rows into registers (16B/lane, coalesced) ---
    uint32_t wi[64], wf[64], wg[64];
#pragma unroll
    for (int k = 0; k < 16; ++k) {
        uint4 v = *(const uint4*)(wpk + (size_t)(0 * 32 + kbase + k) * 2048 + hd * 8);
        wi[k * 4 + 0] = v.x; wi[k * 4 + 1] = v.y; wi[k * 4 + 2] = v.z; wi[k * 4 + 3] = v.w;
    }
#pragma unroll
    for (int k = 0; k < 16; ++k) {
        uint4 v = *(const uint4*)(wpk + (size_t)(1 * 32 + kbase + k) * 2048 + hd * 8);
        wf[k * 4 + 0] = v.x; wf[k * 4 + 1] = v.y; wf[k * 4 + 2] = v.z; wf[k * 4 + 3] = v.w;
    }
#pragma unroll
    for (int k = 0; k < 16; ++k) {
        uint4 v = *(const uint4*)(wpk + (size_t)(2 * 32 + kbase + k) * 2048 + hd * 8);
        wg[k * 4 + 0] = v.x; wg[k * 4 + 1] = v.y; wg[k * 4 + 2] = v.z; wg[k * 4 + 3] = v.w;
    }
    // --- o-gate half-rows into LDS, 16B-unit XOR swizzle (conflict-free) ---
#pragma unroll
    for (int k = 0; k < 16; ++k) {
        uint4 v = *(const uint4*)(wpk + (size_t)(3 * 32 + kbase + k) * 2048 + hd * 8);
        int u = (kbase + k) ^ tmask;
        *(uint4*)(wg4 + hd * 256 + u * 8) = v;
    }

    float c = 0.f, h = 0.f;
    if (q0) {
        if (!first) {
            c = state[b * H_ + hd];
            h = state[B_ * H_ + b * H_ + hd];
        }
        hs[hd] = f2h(h);
    }
    __syncthreads();

    ushort* gxb = gx + (size_t)b * TCc * G4_;

    ushort c_i = 0, c_f = 0, c_g = 0, c_o = 0;
    if (q0) {
        c_i = gxb[hd]; c_f = gxb[256 + hd]; c_g = gxb[512 + hd]; c_o = gxb[768 + hd];
    }

    for (int tl = 0; tl < TCc; ++tl) {
        // prefetch next step's gx (hidden under the dot loop)
        ushort n_i = 0, n_f = 0, n_g = 0, n_o = 0;
        if (q0) {
            const int tn = (tl + 1 < TCc) ? tl + 1 : tl;
            const size_t nb = (size_t)tn * G4_;
            n_i = gxb[nb + hd];       n_f = gxb[nb + 256 + hd];
            n_g = gxb[nb + 512 + hd]; n_o = gxb[nb + 768 + hd];
        }

        float ai, af, ag, ao;
        if (q0) { ai = h2f(c_i); af = h2f(c_f); ag = h2f(c_g); ao = h2f(c_o); }
        else    { ai = 0.f; af = 0.f; ag = 0.f; ao = 0.f; }

#pragma unroll
        for (int k = 0; k < 16; ++k) {
            const int kc = kbase + k;
            uint4 hq = *(const uint4*)(hs + kc * 8);                 // broadcast
            int u = kc ^ tmask;
            uint4 wo = *(const uint4*)(wg4 + hd * 256 + u * 8);      // per-lane
            ai = fdot2(wi[k * 4 + 0], hq.x, ai);
            ai = fdot2(wi[k * 4 + 1], hq.y, ai);
            ai = fdot2(wi[k * 4 + 2], hq.z, ai);
            ai = fdot2(wi[k * 4 + 3], hq.w, ai);
            af = fdot2(wf[k * 4 + 0], hq.x, af);
            af = fdot2(wf[k * 4 + 1], hq.y, af);
            af = fdot2(wf[k * 4 + 2], hq.z, af);
            af = fdot2(wf[k * 4 + 3], hq.w, af);
            ag = fdot2(wg[k * 4 + 0], hq.x, ag);
            ag = fdot2(wg[k * 4 + 1], hq.y, ag);
            ag = fdot2(wg[k * 4 + 2], hq.z, ag);
            ag = fdot2(wg[k * 4 + 3], hq.w, ag);
            ao = fdot2(wo.x, hq.x, ao);
            ao = fdot2(wo.y, hq.y, ao);
            ao = fdot2(wo.z, hq.z, ao);
            ao = fdot2(wo.w, hq.w, ao);
        }

        if (!q0) {
            pex[0][hd] = ai; pex[1][hd] = af; pex[2][hd] = ag; pex[3][hd] = ao;
        }
        __syncthreads();

        if (q0) {
            ai += pex[0][hd]; af += pex[1][hd]; ag += pex[2][hd]; ao += pex[3][hd];

            float si = __builtin_amdgcn_rcpf(1.f + __expf(-ai));
            float sf = __builtin_amdgcn_rcpf(1.f + __expf(-af));
            float so = __builtin_amdgcn_rcpf(1.f + __expf(-ao));
            float eg = __expf(2.f * ag);
            float tg = (eg - 1.f) * __builtin_amdgcn_rcpf(eg + 1.f);
            c = sf * c + si * tg;
            float ec = __expf(2.f * c);
            float tc = (ec - 1.f) * __builtin_amdgcn_rcpf(ec + 1.f);
            h = so * tc;

            ushort hh = f2h(h);
            hs[hd] = hh;
            gxb[(size_t)tl * G4_ + hd] = hh;   // h(t) -> consumed gx row (for proj)
        }
        __syncthreads();

        c_i = n_i; c_f = n_f; c_g = n_g; c_o = n_o;
    }

    if (q0) {
        state[b * H_ + hd]            = c;
        state[B_ * H_ + b * H_ + hd]  = h;
    }
}

// ---------------------------------------------------------------------------
// out[b,t] = sum_hd h[b,t,hd] * Wo[hd] + bo.  h is f16 in gx row slot [0:256).
// Memory-bound: ~64 MB read total.
// ---------------------------------------------------------------------------
__global__ __launch_bounds__(256) void proj_kernel(
    const ushort* __restrict__ gx, const float* __restrict__ Wo,
    const float* __restrict__ bo, float* __restrict__ out, int t0, int TCc) {

    const int lane = threadIdx.x & 63;
    const int wid  = blockIdx.x * 4 + (threadIdx.x >> 6);
    const int nw   = gridDim.x * 4;
    const int rows = B_ * TCc;

    float4 w = *(const float4*)(Wo + lane * 4);
    const float bov = bo[0];

    for (int r = wid; r < rows; r += nw) {
        const ushort* hp = gx + (size_t)r * G4_ + lane * 4;
        ushort4 u = *(const ushort4*)hp;
        float p = h2f(u.x) * w.x + h2f(u.y) * w.y + h2f(u.z) * w.z + h2f(u.w) * w.w;
#pragma unroll
        for (int m = 1; m < 64; m <<= 1) p += __shfl_xor(p, m, 64);
        if (lane == 0) {
            int b  = r / TCc;
            int tl = r - b * TCc;
            out[(size_t)b * T_ + t0 + tl] = p + bov;
        }
    }
}

// ---------------------------------------------------------------------------
extern "C" void kernel_launch(void* const* d_in, const int* in_sizes, int n_in,
                              void* d_out, int out_size, void* d_ws, size_t ws_size,
                              hipStream_t stream) {
    const float* x   = (const float*)d_in[0];
    const float* Wih = (const float*)d_in[1];
    const float* Whh = (const float*)d_in[2];
    const float* bih = (const float*)d_in[3];
    const float* bhh = (const float*)d_in[4];
    const float* Wo  = (const float*)d_in[5];
    const float* bo  = (const float*)d_in[6];
    float* out = (float*)d_out;

    char* ws = (char*)d_ws;
    ushort* wpk   = (ushort*)ws;                              // 512 KB
    float*  state = (float*)(ws + 512 * 1024);                // 128 KB
    ushort* gxb   = (ushort*)(ws + 512 * 1024 + 128 * 1024);  // rest: gx chunks

    size_t avail = (ws_size > 640 * 1024) ? ws_size - 640 * 1024 : 0;
    long long tcmax = (long long)(avail / ((size_t)B_ * G4_ * 2));
    int TC = (tcmax > T_) ? T_ : (int)tcmax;
    TC &= ~63;               // multiple of 64
    if (TC < 64) TC = 64;    // minimum viable chunk

    repack_kernel<<<1024, 256, 0, stream>>>(Whh, wpk);

    for (int t0 = 0; t0 < T_; t0 += TC) {
        int TCc = (T_ - t0 < TC) ? (T_ - t0) : TC;
        dim3 g1((B_ * TCc) / 32, 4);
        gx_kernel<<<g1, 256, 0, stream>>>(x, Wih, bih, bhh, gxb, t0, TCc);
        lstm_kernel<<<B_, 512, 0, stream>>>(wpk, gxb, state, TCc, t0 == 0 ? 1 : 0);
        proj_kernel<<<256, 256, 0, stream>>>(gxb, Wo, bo, out, t0, TCc);
    }
    (void)in_sizes; (void)n_in; (void)out_size;
}

// Round 3
// 3447.829 us; speedup vs baseline: 1.7226x; 1.0131x over previous
//
#include <hip/hip_runtime.h>
#include <hip/hip_fp16.h>

#define B_  64
#define T_  2048
#define I_  64
#define H_  256
#define G4_ 1024   // 4*H

typedef _Float16 h2v __attribute__((ext_vector_type(2)));

__device__ __forceinline__ float fdot2(uint32_t a, uint32_t b, float c) {
#if __has_builtin(__builtin_amdgcn_fdot2)
    return __builtin_amdgcn_fdot2(__builtin_bit_cast(h2v, a), __builtin_bit_cast(h2v, b), c, false);
#else
    h2v ha = __builtin_bit_cast(h2v, a), hb = __builtin_bit_cast(h2v, b);
    return c + (float)ha.x * (float)hb.x + (float)ha.y * (float)hb.y;
#endif
}

__device__ __forceinline__ ushort f2h(float v) {
    return __builtin_bit_cast(ushort, (_Float16)v);
}
__device__ __forceinline__ float h2f(ushort v) {
    return (float)__builtin_bit_cast(_Float16, v);
}

// ---------------------------------------------------------------------------
// Repack W_hh fp32 [1024][256] -> f16 wpk[g][kc][h][j]  (g=gate, kc=K/8 chunk,
// h=hdim 0..255, j=0..7).  Coalesced 16B/lane preload in the LSTM kernel.
// ---------------------------------------------------------------------------
__global__ void repack_kernel(const float* __restrict__ Whh, ushort* __restrict__ wpk) {
    int o  = blockIdx.x * 256 + threadIdx.x;   // 0 .. 262143
    int j  = o & 7;
    int h  = (o >> 3) & 255;
    int kc = (o >> 11) & 31;
    int g  = o >> 16;
    float v = Whh[(g * 256 + h) * 256 + kc * 8 + j];
    wpk[o] = f2h(v);
}

// ---------------------------------------------------------------------------
// gx = x @ W_ih^T + b_ih + b_hh  (f16 out), one chunk of TCc timesteps.
// grid = ((64*TCc)/32, 4), block = 256.  Tile: 32 (b,t) rows x 256 gate rows.
// ---------------------------------------------------------------------------
__global__ __launch_bounds__(256) void gx_kernel(
    const float* __restrict__ x, const float* __restrict__ Wih,
    const float* __restrict__ bih, const float* __restrict__ bhh,
    ushort* __restrict__ gx, int t0, int TCc) {

    __shared__ float xs[32][64];
    const int bt0 = blockIdx.x * 32;
    const int row = blockIdx.y * 256 + threadIdx.x;

    // vectorized x tile load: 512 float4
    for (int i = threadIdx.x; i < 512; i += 256) {
        int r  = i >> 4, c4 = i & 15;
        int bt = bt0 + r;
        int b  = bt / TCc;
        int tl = bt - b * TCc;
        *(float4*)(&xs[r][c4 * 4]) =
            *(const float4*)(&x[(((size_t)b * T_) + t0 + tl) * I_ + c4 * 4]);
    }
    __syncthreads();

    float w[64];
#pragma unroll
    for (int k = 0; k < 64; ++k) w[k] = Wih[row * I_ + k];
    const float bias = bih[row] + bhh[row];

    for (int i = 0; i < 32; ++i) {
        float acc = bias;
#pragma unroll
        for (int k4 = 0; k4 < 16; ++k4) {
            float4 xq = *(const float4*)(&xs[i][k4 * 4]);
            acc = fmaf(w[k4 * 4 + 0], xq.x, acc);
            acc = fmaf(w[k4 * 4 + 1], xq.y, acc);
            acc = fmaf(w[k4 * 4 + 2], xq.z, acc);
            acc = fmaf(w[k4 * 4 + 3], xq.w, acc);
        }
        gx[(size_t)(bt0 + i) * G4_ + row] = f2h(acc);
    }
}

// ---------------------------------------------------------------------------
// Persistent per-batch LSTM.  64 blocks x 512 threads, waves_per_eu pinned to
// 2 => 256-VGPR arch budget: i/f/g half-rows (192 dwords) stay in arch VGPRs
// (round-2 regression: launch_bounds(512,2) gave a 128-VGPR budget and the
// compiler demoted the weight arrays to AGPRs -> a v_accvgpr_read per use).
// Thread pair (hd, hd+256) splits K=256; o-gate half-rows stream from LDS
// (128 KB, XOR-swizzled, 0 conflicts).  q=1 hands partials to q=0 via one
// packed float4; q=0 owns c,h + elementwise.  h(t) -> hbuf (f16) for proj.
// ---------------------------------------------------------------------------
__global__ __attribute__((amdgpu_flat_work_group_size(512, 512), amdgpu_waves_per_eu(2, 2)))
void lstm_kernel(
    const ushort* __restrict__ wpk, const ushort* __restrict__ gx,
    ushort* __restrict__ hbuf,     // [B][TCc][H] f16
    float* __restrict__ state,     // [2][64][256]: c then h
    int TCc, int first) {

    __shared__ __align__(16) ushort wg4[256 * 256];  // o-gate rows, 128 KB
    __shared__ __align__(16) ushort hs[256];         // h(t-1) as f16
    __shared__ __align__(16) float pex[256][4];      // q=1 -> q=0 partials

    const int tid   = threadIdx.x;
    const int hd    = tid & 255;       // owned h-dim
    const int q     = tid >> 8;        // K-half: 0 -> k 0..127, 1 -> k 128..255
    const int kbase = q << 4;          // first kc chunk (8 h's each) of this half
    const int tmask = hd & 31;
    const int b     = blockIdx.x;
    const bool q0   = (q == 0);

    // --- preload i/f/g gate half-rows into registers (16B/lane, coalesced) ---
    uint32_t wi[64], wf[64], wg[64];
#pragma unroll
    for (int k = 0; k < 16; ++k) {
        uint4 v = *(const uint4*)(wpk + (size_t)(0 * 32 + kbase + k) * 2048 + hd * 8);
        wi[k * 4 + 0] = v.x; wi[k * 4 + 1] = v.y; wi[k * 4 + 2] = v.z; wi[k * 4 + 3] = v.w;
    }
#pragma unroll
    for (int k = 0; k < 16; ++k) {
        uint4 v = *(const uint4*)(wpk + (size_t)(1 * 32 + kbase + k) * 2048 + hd * 8);
        wf[k * 4 + 0] = v.x; wf[k * 4 + 1] = v.y; wf[k * 4 + 2] = v.z; wf[k * 4 + 3] = v.w;
    }
#pragma unroll
    for (int k = 0; k < 16; ++k) {
        uint4 v = *(const uint4*)(wpk + (size_t)(2 * 32 + kbase + k) * 2048 + hd * 8);
        wg[k * 4 + 0] = v.x; wg[k * 4 + 1] = v.y; wg[k * 4 + 2] = v.z; wg[k * 4 + 3] = v.w;
    }
    // --- o-gate half-rows into LDS, 16B-unit XOR swizzle (conflict-free) ---
#pragma unroll
    for (int k = 0; k < 16; ++k) {
        uint4 v = *(const uint4*)(wpk + (size_t)(3 * 32 + kbase + k) * 2048 + hd * 8);
        int u = (kbase + k) ^ tmask;
        *(uint4*)(wg4 + hd * 256 + u * 8) = v;
    }

    float c = 0.f, h = 0.f;
    if (q0) {
        if (!first) {
            c = state[b * H_ + hd];
            h = state[B_ * H_ + b * H_ + hd];
        }
        hs[hd] = f2h(h);
    }
    __syncthreads();

    const ushort* gxb = gx + (size_t)b * TCc * G4_;
    ushort* hb = hbuf + (size_t)b * TCc * H_;

    ushort c_i = 0, c_f = 0, c_g = 0, c_o = 0;
    if (q0) {
        c_i = gxb[hd]; c_f = gxb[256 + hd]; c_g = gxb[512 + hd]; c_o = gxb[768 + hd];
    }

    for (int tl = 0; tl < TCc; ++tl) {
        // prefetch next step's gx (hidden under the dot loop)
        ushort n_i = 0, n_f = 0, n_g = 0, n_o = 0;
        if (q0) {
            const int tn = (tl + 1 < TCc) ? tl + 1 : tl;
            const size_t nb = (size_t)tn * G4_;
            n_i = gxb[nb + hd];       n_f = gxb[nb + 256 + hd];
            n_g = gxb[nb + 512 + hd]; n_o = gxb[nb + 768 + hd];
        }

        float ai, af, ag, ao;
        if (q0) { ai = h2f(c_i); af = h2f(c_f); ag = h2f(c_g); ao = h2f(c_o); }
        else    { ai = 0.f; af = 0.f; ag = 0.f; ao = 0.f; }

#pragma unroll
        for (int k = 0; k < 16; ++k) {
            const int kc = kbase + k;
            uint4 hq = *(const uint4*)(hs + kc * 8);                 // broadcast
            int u = kc ^ tmask;
            uint4 wo = *(const uint4*)(wg4 + hd * 256 + u * 8);      // per-lane
            ai = fdot2(wi[k * 4 + 0], hq.x, ai);
            ai = fdot2(wi[k * 4 + 1], hq.y, ai);
            ai = fdot2(wi[k * 4 + 2], hq.z, ai);
            ai = fdot2(wi[k * 4 + 3], hq.w, ai);
            af = fdot2(wf[k * 4 + 0], hq.x, af);
            af = fdot2(wf[k * 4 + 1], hq.y, af);
            af = fdot2(wf[k * 4 + 2], hq.z, af);
            af = fdot2(wf[k * 4 + 3], hq.w, af);
            ag = fdot2(wg[k * 4 + 0], hq.x, ag);
            ag = fdot2(wg[k * 4 + 1], hq.y, ag);
            ag = fdot2(wg[k * 4 + 2], hq.z, ag);
            ag = fdot2(wg[k * 4 + 3], hq.w, ag);
            ao = fdot2(wo.x, hq.x, ao);
            ao = fdot2(wo.y, hq.y, ao);
            ao = fdot2(wo.z, hq.z, ao);
            ao = fdot2(wo.w, hq.w, ao);
        }

        if (!q0) {
            pex[hd][0] = ai; pex[hd][1] = af; pex[hd][2] = ag; pex[hd][3] = ao;
        }
        __syncthreads();

        if (q0) {
            float4 px = *(const float4*)(&pex[hd][0]);
            ai += px.x; af += px.y; ag += px.z; ao += px.w;

            float si = __builtin_amdgcn_rcpf(1.f + __expf(-ai));
            float sf = __builtin_amdgcn_rcpf(1.f + __expf(-af));
            float so = __builtin_amdgcn_rcpf(1.f + __expf(-ao));
            float eg = __expf(2.f * ag);
            float tg = (eg - 1.f) * __builtin_amdgcn_rcpf(eg + 1.f);
            c = sf * c + si * tg;
            float ec = __expf(2.f * c);
            float tc = (ec - 1.f) * __builtin_amdgcn_rcpf(ec + 1.f);
            h = so * tc;

            ushort hh = f2h(h);
            hs[hd] = hh;
            hb[(size_t)tl * H_ + hd] = hh;
        }
        __syncthreads();

        c_i = n_i; c_f = n_f; c_g = n_g; c_o = n_o;
    }

    if (q0) {
        state[b * H_ + hd]            = c;
        state[B_ * H_ + b * H_ + hd]  = h;
    }
}

// ---------------------------------------------------------------------------
// out[b,t] = sum_hd h[b,t,hd] * Wo[hd] + bo.  h f16 rows, fully dense reads.
// ---------------------------------------------------------------------------
__global__ __launch_bounds__(256) void proj_kernel(
    const ushort* __restrict__ hbuf, const float* __restrict__ Wo,
    const float* __restrict__ bo, float* __restrict__ out, int t0, int TCc) {

    const int lane = threadIdx.x & 63;
    const int wid  = blockIdx.x * 4 + (threadIdx.x >> 6);
    const int nw   = gridDim.x * 4;
    const int rows = B_ * TCc;

    float4 w = *(const float4*)(Wo + lane * 4);
    const float bov = bo[0];

    for (int r = wid; r < rows; r += nw) {
        const ushort* hp = hbuf + (size_t)r * H_ + lane * 4;
        ushort4 u = *(const ushort4*)hp;
        float p = h2f(u.x) * w.x + h2f(u.y) * w.y + h2f(u.z) * w.z + h2f(u.w) * w.w;
#pragma unroll
        for (int m = 1; m < 64; m <<= 1) p += __shfl_xor(p, m, 64);
        if (lane == 0) {
            int b  = r / TCc;
            int tl = r - b * TCc;
            out[(size_t)b * T_ + t0 + tl] = p + bov;
        }
    }
}

// ---------------------------------------------------------------------------
extern "C" void kernel_launch(void* const* d_in, const int* in_sizes, int n_in,
                              void* d_out, int out_size, void* d_ws, size_t ws_size,
                              hipStream_t stream) {
    const float* x   = (const float*)d_in[0];
    const float* Wih = (const float*)d_in[1];
    const float* Whh = (const float*)d_in[2];
    const float* bih = (const float*)d_in[3];
    const float* bhh = (const float*)d_in[4];
    const float* Wo  = (const float*)d_in[5];
    const float* bo  = (const float*)d_in[6];
    float* out = (float*)d_out;

    char* ws = (char*)d_ws;
    ushort* wpk   = (ushort*)ws;                              // 512 KB
    float*  state = (float*)(ws + 512 * 1024);                // 128 KB
    char*   dyn   = ws + 640 * 1024;                          // gx + hbuf chunks

    size_t avail = (ws_size > 640 * 1024) ? ws_size - 640 * 1024 : 0;
    // per (b,t): gx row 2048 B + hbuf row 512 B
    long long tcmax = (long long)(avail / ((size_t)B_ * (G4_ + H_) * 2));
    int TC = (tcmax > T_) ? T_ : (int)tcmax;
    TC &= ~63;               // multiple of 64
    if (TC < 64) TC = 64;    // minimum viable chunk

    repack_kernel<<<1024, 256, 0, stream>>>(Whh, wpk);

    for (int t0 = 0; t0 < T_; t0 += TC) {
        int TCc = (T_ - t0 < TC) ? (T_ - t0) : TC;
        ushort* gxb  = (ushort*)dyn;
        ushort* hbuf = (ushort*)(dyn + (size_t)B_ * TCc * G4_ * 2);
        dim3 g1((B_ * TCc) / 32, 4);
        gx_kernel<<<g1, 256, 0, stream>>>(x, Wih, bih, bhh, gxb, t0, TCc);
        lstm_kernel<<<B_, 512, 0, stream>>>(wpk, gxb, hbuf, state, TCc, t0 == 0 ? 1 : 0);
        proj_kernel<<<256, 256, 0, stream>>>(hbuf, Wo, bo, out, t0, TCc);
    }
    (void)in_sizes; (void)n_in; (void)out_size;
}